// Round 8
// baseline (312.740 us; speedup 1.0000x reference)
//
#include <hip/hip_runtime.h>

// out = B @ (X @ W):
//   wtrans: Wt_bf16[n][k] = bf16(W[k][n])
//   hist/scan/fill: CSR build
//   proj:   x_proj_bf16 = bf16(X @ W); LDS-free MFMA; A-frags direct from
//           fp32 X + scalar f2bf pack (NO inline-asm cvt_pk — r7 NaN suspect);
//           B-frags from L2-resident Wt; lane-permuted packed epilogue stores
//   gather: wave per out row, batched independent 512B bf16-row gathers,
//           fp32 accumulate, direct fp32 out writes (unpermuting)

typedef short bf16x8 __attribute__((ext_vector_type(8)));
typedef float f32x4  __attribute__((ext_vector_type(4)));

static __device__ __forceinline__ unsigned short f2bf(float f) {
    union { float f; unsigned u; } a; a.f = f;
    unsigned r = a.u + 0x7FFFu + ((a.u >> 16) & 1u);   // RNE
    return (unsigned short)(r >> 16);
}

static __device__ __forceinline__ float bf2f(unsigned short h) {
    union { unsigned u; float f; } a; a.u = (unsigned)h << 16;
    return a.f;
}

static __device__ __forceinline__ unsigned pack2(float f0, float f1) {
    return (unsigned)f2bf(f0) | ((unsigned)f2bf(f1) << 16);
}

// pack 8 fp32 -> bf16x8 (scalar path, proven in rounds 3-6)
static __device__ __forceinline__ bf16x8 cvt8(float4 lo, float4 hi) {
    union { bf16x8 v; unsigned u[4]; } r;
    r.u[0] = pack2(lo.x, lo.y);
    r.u[1] = pack2(lo.z, lo.w);
    r.u[2] = pack2(hi.x, hi.y);
    r.u[3] = pack2(hi.z, hi.w);
    return r.v;
}

__global__ __launch_bounds__(256) void wtrans_kernel(
    const float* __restrict__ W, unsigned short* __restrict__ Wt)
{
    int k = blockIdx.x;
    int n = threadIdx.x;
    Wt[(size_t)n * 256 + k] = f2bf(W[(size_t)k * 256 + n]);
}

__global__ __launch_bounds__(256) void hist_kernel(
    const int* __restrict__ b_rows, int* __restrict__ cnt, int nnz)
{
    int i = blockIdx.x * 256 + threadIdx.x;
    if (i < nnz) atomicAdd(&cnt[b_rows[i]], 1);
}

__global__ __launch_bounds__(1024) void scan_part_kernel(
    const int* __restrict__ cnt, int* __restrict__ partials, int M)
{
    int tid = threadIdx.x;
    int base = blockIdx.x * 4096;
    int s = 0;
    #pragma unroll
    for (int k = 0; k < 4; ++k) {
        int i = base + k * 1024 + tid;
        if (i < M) s += cnt[i];
    }
    #pragma unroll
    for (int d = 1; d < 64; d <<= 1) s += __shfl_xor(s, d);
    __shared__ int wsum[16];
    int lane = tid & 63, wid = tid >> 6;
    if (lane == 0) wsum[wid] = s;
    __syncthreads();
    if (tid == 0) {
        int t = 0;
        #pragma unroll
        for (int w = 0; w < 16; ++w) t += wsum[w];
        partials[blockIdx.x] = t;
    }
}

__global__ __launch_bounds__(64) void scan_mid_kernel(
    int* __restrict__ partials, int* __restrict__ off, int np, int M)
{
    int lane = threadIdx.x;
    int v = (lane < np) ? partials[lane] : 0;
    int x = v;
    #pragma unroll
    for (int d = 1; d < 64; d <<= 1) { int y = __shfl_up(x, d); if (lane >= d) x += y; }
    if (lane < np) partials[lane] = x - v;
    if (lane == 63) off[M] = x;
}

__global__ __launch_bounds__(1024) void scan_apply_kernel(
    const int* __restrict__ cnt, const int* __restrict__ partials,
    int* __restrict__ off, int* __restrict__ cursor, int M)
{
    int tid = threadIdx.x;
    int base = blockIdx.x * 4096 + tid * 4;
    int4 v = make_int4(0, 0, 0, 0);
    if (base + 3 < M) v = *reinterpret_cast<const int4*>(cnt + base);
    else {
        if (base + 0 < M) v.x = cnt[base + 0];
        if (base + 1 < M) v.y = cnt[base + 1];
        if (base + 2 < M) v.z = cnt[base + 2];
    }
    int s1 = v.x + v.y, s2 = s1 + v.z, tsum = s2 + v.w;
    int x = tsum;
    int lane = tid & 63, wid = tid >> 6;
    #pragma unroll
    for (int d = 1; d < 64; d <<= 1) { int y = __shfl_up(x, d); if (lane >= d) x += y; }
    __shared__ int wsum[16];
    if (lane == 63) wsum[wid] = x;
    __syncthreads();
    if (wid == 0 && lane < 16) {
        int w = wsum[lane];
        int xx = w;
        #pragma unroll
        for (int d = 1; d < 16; d <<= 1) { int y = __shfl_up(xx, d); if (lane >= d) xx += y; }
        wsum[lane] = xx - w;
    }
    __syncthreads();
    int excl = (x - tsum) + wsum[wid] + partials[blockIdx.x];
    int o0 = excl, o1 = excl + v.x, o2 = excl + s1, o3 = excl + s2;
    if (base + 0 < M) { off[base + 0] = o0; cursor[base + 0] = o0; }
    if (base + 1 < M) { off[base + 1] = o1; cursor[base + 1] = o1; }
    if (base + 2 < M) { off[base + 2] = o2; cursor[base + 2] = o2; }
    if (base + 3 < M) { off[base + 3] = o3; cursor[base + 3] = o3; }
}

__global__ __launch_bounds__(256) void fill_kernel(
    const float* __restrict__ b_vals, const int* __restrict__ b_rows,
    const int* __restrict__ b_cols, int* __restrict__ cursor,
    int* __restrict__ csr_col, float* __restrict__ csr_val, int nnz)
{
    int i = blockIdx.x * 256 + threadIdx.x;
    if (i < nnz) {
        int r = b_rows[i];
        int pos = atomicAdd(&cursor[r], 1);
        csr_col[pos] = b_cols[i];
        csr_val[pos] = b_vals[i];
    }
}

// x_proj = bf16(X @ W). Block = 4 waves over the SAME 32 rows; wave w owns
// cols [64w, 64w+64). LDS-free: A-frags direct from fp32 X + scalar pack,
// B-frags from Wt (L2). Requires N % 32 == 0.
// Storage permutation (shared contract with gather_kernel): row halfword
// range [w*64 + a*4, +4) holds true channels {64w + a + 16t : t=0..3}.
__global__ __launch_bounds__(256, 4) void proj_kernel(
    const float* __restrict__ X, const unsigned short* __restrict__ Wt,
    unsigned short* __restrict__ xp)
{
    int lane = threadIdx.x & 63, w = threadIdx.x >> 6;
    int r0 = blockIdx.x * 32;
    int arow = lane & 15;
    int kg = lane >> 4;             // k-group 0..3

    const float* a0p = X + (size_t)(r0 + arow) * 256 + kg * 8;        // m=0 row
    const float* a1p = a0p + 16 * 256;                                 // m=1 row
    const char*  wt  = reinterpret_cast<const char*>(Wt);
    int nbase = w * 64;
    size_t boff = (size_t)(nbase + arow) * 512 + kg * 16;              // t=0 frag

    f32x4 acc[2][4] = {};

    #pragma unroll
    for (int s = 0; s < 8; ++s) {
        // A: 8 fp32 per m (two float4), independent of everything prior
        float4 a0l = *reinterpret_cast<const float4*>(a0p + s * 32);
        float4 a0h = *reinterpret_cast<const float4*>(a0p + s * 32 + 4);
        float4 a1l = *reinterpret_cast<const float4*>(a1p + s * 32);
        float4 a1h = *reinterpret_cast<const float4*>(a1p + s * 32 + 4);
        // B: 4 frags from Wt
        bf16x8 b[4];
        #pragma unroll
        for (int t = 0; t < 4; ++t)
            b[t] = *reinterpret_cast<const bf16x8*>(wt + boff + (size_t)t * 16 * 512 + s * 64);

        bf16x8 a0 = cvt8(a0l, a0h);
        bf16x8 a1 = cvt8(a1l, a1h);

        #pragma unroll
        for (int t = 0; t < 4; ++t) {
            acc[0][t] = __builtin_amdgcn_mfma_f32_16x16x32_bf16(a0, b[t], acc[0][t], 0, 0, 0);
            acc[1][t] = __builtin_amdgcn_mfma_f32_16x16x32_bf16(a1, b[t], acc[1][t], 0, 0, 0);
        }
    }

    // packed permuted epilogue: one 8B store per (m, reg)
    int hi = lane >> 4;
    #pragma unroll
    for (int m = 0; m < 2; ++m) {
        #pragma unroll
        for (int rr = 0; rr < 4; ++rr) {
            int row = r0 + m * 16 + hi * 4 + rr;
            ushort4 h;
            h.x = f2bf(acc[m][0][rr]);
            h.y = f2bf(acc[m][1][rr]);
            h.z = f2bf(acc[m][2][rr]);
            h.w = f2bf(acc[m][3][rr]);
            *reinterpret_cast<ushort4*>(xp + (size_t)row * 256 + nbase + arow * 4) = h;
        }
    }
}

// wave per out row; batched independent bf16-row gathers; fp32 out (unpermute).
__global__ __launch_bounds__(256) void gather_kernel(
    const unsigned short* __restrict__ xp, const float* __restrict__ csr_val,
    const int* __restrict__ csr_col, const int* __restrict__ off,
    float* __restrict__ out, int M)
{
    int row = blockIdx.x * 4 + (threadIdx.x >> 6);
    if (row >= M) return;
    int lane = threadIdx.x & 63;

    int s = off[row], e = off[row + 1];
    float a0 = 0.f, a1 = 0.f, a2 = 0.f, a3 = 0.f;

    for (int j = s; j < e; j += 8) {
        int nb = e - j;                         // wave-uniform
        int c[8]; float v[8]; ushort4 xs[8];
        #pragma unroll
        for (int t = 0; t < 8; ++t)
            if (t < nb) { c[t] = csr_col[j + t]; v[t] = csr_val[j + t]; }
        #pragma unroll
        for (int t = 0; t < 8; ++t)
            if (t < nb)
                xs[t] = *reinterpret_cast<const ushort4*>(
                    xp + (size_t)c[t] * 256 + lane * 4);   // 8B/lane, independent
        #pragma unroll
        for (int t = 0; t < 8; ++t)
            if (t < nb) {
                a0 += v[t] * bf2f(xs[t].x);
                a1 += v[t] * bf2f(xs[t].y);
                a2 += v[t] * bf2f(xs[t].z);
                a3 += v[t] * bf2f(xs[t].w);
            }
    }

    // lane holds true channels {64*(lane>>4) + (lane&15) + 16*t}
    int col0 = (lane >> 4) * 64 + (lane & 15);
    float* o = out + (size_t)row * 256;
    o[col0 +  0] = a0;
    o[col0 + 16] = a1;
    o[col0 + 32] = a2;
    o[col0 + 48] = a3;
}

extern "C" void kernel_launch(void* const* d_in, const int* in_sizes, int n_in,
                              void* d_out, int out_size, void* d_ws, size_t ws_size,
                              hipStream_t stream) {
    const float* x_src  = (const float*)d_in[0];
    const float* W      = (const float*)d_in[1];
    const float* b_vals = (const float*)d_in[2];
    const int*   b_rows = (const int*)d_in[3];
    const int*   b_cols = (const int*)d_in[4];

    const int C = 256;
    const int M = out_size / C;
    const int nnz = in_sizes[2];
    const int N = in_sizes[0] / C;

    char* ws = (char*)d_ws;
    unsigned short* Wt = (unsigned short*)ws;           ws += 256 * 256 * 2;
    int*   cnt     = (int*)ws;                          ws += (size_t)M * 4;
    int*   off     = (int*)ws;                          ws += (size_t)(M + 1) * 4;
    int*   cursor  = (int*)ws;                          ws += (size_t)M * 4;
    int*   partials= (int*)ws;                          ws += 64 * 4;
    int*   csr_col = (int*)ws;                          ws += (size_t)nnz * 4;
    float* csr_val = (float*)ws;                        ws += (size_t)nnz * 4;
    ws = (char*)(((size_t)ws + 63) & ~(size_t)63);
    unsigned short* xp = (unsigned short*)ws;           // N*512 bytes (~102 MB)

    float* out = (float*)d_out;

    hipMemsetAsync(cnt, 0, (size_t)M * 4, stream);

    wtrans_kernel<<<256, 256, 0, stream>>>(W, Wt);

    int nblk_nnz = (nnz + 255) / 256;
    hist_kernel<<<nblk_nnz, 256, 0, stream>>>(b_rows, cnt, nnz);

    int nb = (M + 4095) / 4096;
    scan_part_kernel<<<nb, 1024, 0, stream>>>(cnt, partials, M);
    scan_mid_kernel<<<1, 64, 0, stream>>>(partials, off, nb, M);
    scan_apply_kernel<<<nb, 1024, 0, stream>>>(cnt, partials, off, cursor, M);

    fill_kernel<<<nblk_nnz, 256, 0, stream>>>(b_vals, b_rows, b_cols, cursor,
                                              csr_col, csr_val, nnz);

    proj_kernel<<<N / 32, 256, 0, stream>>>(x_src, Wt, xp);

    gather_kernel<<<(M + 3) / 4, 256, 0, stream>>>(xp, csr_val, csr_col, off, out, M);
}

// Round 9
// 208.508 us; speedup vs baseline: 1.4999x; 1.4999x over previous
//
#include <hip/hip_runtime.h>

// out = B @ (X @ W):
//   wtrans: Wt_bf16[n][k] = bf16(W[k][n])
//   hist/scan/fill: CSR build
//   proj2:  x_proj_bf16 = bf16(X @ W). W lives ENTIRELY in LDS (128 KB,
//           XOR-swizzled, staged once per block); waves stream 16-row A-tiles
//           from fp32 X with 16 independent loads; 128 MFMA/tile vs LDS B;
//           lane-permuted packed epilogue stores (contract shared with gather)
//   gather: wave per out row, batched independent 512B bf16-row gathers,
//           fp32 accumulate, direct fp32 out writes (unpermuting)

typedef short bf16x8 __attribute__((ext_vector_type(8)));
typedef float f32x4  __attribute__((ext_vector_type(4)));

static __device__ __forceinline__ unsigned short f2bf(float f) {
    union { float f; unsigned u; } a; a.f = f;
    unsigned r = a.u + 0x7FFFu + ((a.u >> 16) & 1u);   // RNE
    return (unsigned short)(r >> 16);
}

static __device__ __forceinline__ float bf2f(unsigned short h) {
    union { unsigned u; float f; } a; a.u = (unsigned)h << 16;
    return a.f;
}

static __device__ __forceinline__ unsigned pack2(float f0, float f1) {
    return (unsigned)f2bf(f0) | ((unsigned)f2bf(f1) << 16);
}

static __device__ __forceinline__ bf16x8 cvt8(float4 lo, float4 hi) {
    union { bf16x8 v; unsigned u[4]; } r;
    r.u[0] = pack2(lo.x, lo.y);
    r.u[1] = pack2(lo.z, lo.w);
    r.u[2] = pack2(hi.x, hi.y);
    r.u[3] = pack2(hi.z, hi.w);
    return r.v;
}

__global__ __launch_bounds__(256) void wtrans_kernel(
    const float* __restrict__ W, unsigned short* __restrict__ Wt)
{
    int k = blockIdx.x;
    int n = threadIdx.x;
    Wt[(size_t)n * 256 + k] = f2bf(W[(size_t)k * 256 + n]);
}

__global__ __launch_bounds__(256) void hist_kernel(
    const int* __restrict__ b_rows, int* __restrict__ cnt, int nnz)
{
    int i = blockIdx.x * 256 + threadIdx.x;
    if (i < nnz) atomicAdd(&cnt[b_rows[i]], 1);
}

__global__ __launch_bounds__(1024) void scan_part_kernel(
    const int* __restrict__ cnt, int* __restrict__ partials, int M)
{
    int tid = threadIdx.x;
    int base = blockIdx.x * 4096;
    int s = 0;
    #pragma unroll
    for (int k = 0; k < 4; ++k) {
        int i = base + k * 1024 + tid;
        if (i < M) s += cnt[i];
    }
    #pragma unroll
    for (int d = 1; d < 64; d <<= 1) s += __shfl_xor(s, d);
    __shared__ int wsum[16];
    int lane = tid & 63, wid = tid >> 6;
    if (lane == 0) wsum[wid] = s;
    __syncthreads();
    if (tid == 0) {
        int t = 0;
        #pragma unroll
        for (int w = 0; w < 16; ++w) t += wsum[w];
        partials[blockIdx.x] = t;
    }
}

__global__ __launch_bounds__(64) void scan_mid_kernel(
    int* __restrict__ partials, int* __restrict__ off, int np, int M)
{
    int lane = threadIdx.x;
    int v = (lane < np) ? partials[lane] : 0;
    int x = v;
    #pragma unroll
    for (int d = 1; d < 64; d <<= 1) { int y = __shfl_up(x, d); if (lane >= d) x += y; }
    if (lane < np) partials[lane] = x - v;
    if (lane == 63) off[M] = x;
}

__global__ __launch_bounds__(1024) void scan_apply_kernel(
    const int* __restrict__ cnt, const int* __restrict__ partials,
    int* __restrict__ off, int* __restrict__ cursor, int M)
{
    int tid = threadIdx.x;
    int base = blockIdx.x * 4096 + tid * 4;
    int4 v = make_int4(0, 0, 0, 0);
    if (base + 3 < M) v = *reinterpret_cast<const int4*>(cnt + base);
    else {
        if (base + 0 < M) v.x = cnt[base + 0];
        if (base + 1 < M) v.y = cnt[base + 1];
        if (base + 2 < M) v.z = cnt[base + 2];
    }
    int s1 = v.x + v.y, s2 = s1 + v.z, tsum = s2 + v.w;
    int x = tsum;
    int lane = tid & 63, wid = tid >> 6;
    #pragma unroll
    for (int d = 1; d < 64; d <<= 1) { int y = __shfl_up(x, d); if (lane >= d) x += y; }
    __shared__ int wsum[16];
    if (lane == 63) wsum[wid] = x;
    __syncthreads();
    if (wid == 0 && lane < 16) {
        int w = wsum[lane];
        int xx = w;
        #pragma unroll
        for (int d = 1; d < 16; d <<= 1) { int y = __shfl_up(xx, d); if (lane >= d) xx += y; }
        wsum[lane] = xx - w;
    }
    __syncthreads();
    int excl = (x - tsum) + wsum[wid] + partials[blockIdx.x];
    int o0 = excl, o1 = excl + v.x, o2 = excl + s1, o3 = excl + s2;
    if (base + 0 < M) { off[base + 0] = o0; cursor[base + 0] = o0; }
    if (base + 1 < M) { off[base + 1] = o1; cursor[base + 1] = o1; }
    if (base + 2 < M) { off[base + 2] = o2; cursor[base + 2] = o2; }
    if (base + 3 < M) { off[base + 3] = o3; cursor[base + 3] = o3; }
}

__global__ __launch_bounds__(256) void fill_kernel(
    const float* __restrict__ b_vals, const int* __restrict__ b_rows,
    const int* __restrict__ b_cols, int* __restrict__ cursor,
    int* __restrict__ csr_col, float* __restrict__ csr_val, int nnz)
{
    int i = blockIdx.x * 256 + threadIdx.x;
    if (i < nnz) {
        int r = b_rows[i];
        int pos = atomicAdd(&cursor[r], 1);
        csr_col[pos] = b_cols[i];
        csr_val[pos] = b_vals[i];
    }
}

// x_proj = bf16(X @ W) with W entirely in LDS.
// Block = 512 threads (8 waves), LDS = full Wt (128 KB) XOR-swizzled:
//   LDS byte(n, koff) = n*512 + (koff ^ ((n&7)<<4))      koff = k*2
// Each wave processes 16-row tiles: tile = blk*8*tpw + it*8 + wid.
// Requires N % 16 == 0.
// xp storage permutation (contract with gather_kernel): row halfword
// [g*64 + a*4 + t] holds true channel {64g + a + 16t}, a=0..15, t=0..3.
__global__ __launch_bounds__(512, 2) void proj2_kernel(
    const float* __restrict__ X, const unsigned short* __restrict__ Wt,
    unsigned short* __restrict__ xp, int ntiles, int tpw)
{
    __shared__ __align__(16) unsigned char wlds[256 * 512];   // 128 KB

    int tid = threadIdx.x;
    int lane = tid & 63, wid = tid >> 6;

    // ---- stage Wt -> LDS (reg-staged 16B chunks, swizzled store)
    const char* wtg = reinterpret_cast<const char*>(Wt);
    #pragma unroll
    for (int itc = 0; itc < 16; ++itc) {
        int c = tid + itc * 512;               // chunk 0..8191
        int n = c >> 5, j = c & 31;
        uint4 w16 = *reinterpret_cast<const uint4*>(wtg + (size_t)n * 512 + j * 16);
        int b = n * 512 + ((j * 16) ^ ((n & 7) << 4));
        *reinterpret_cast<uint4*>(wlds + b) = w16;
    }
    __syncthreads();

    int arow = lane & 15;
    int kg = lane >> 4;                        // 0..3
    int xo = (arow & 7) << 4;                  // read-side swizzle (n&7 == arow&7)

    for (int it = 0; it < tpw; ++it) {
        int tile = blockIdx.x * (tpw << 3) + (it << 3) + wid;
        if (tile >= ntiles) break;
        int R = tile * 16;

        const float* ap = X + (size_t)(R + arow) * 256 + kg * 8;
        float4 buf[16];
        #pragma unroll
        for (int s = 0; s < 8; ++s) {          // 16 independent 16B loads
            buf[2 * s]     = *reinterpret_cast<const float4*>(ap + s * 32);
            buf[2 * s + 1] = *reinterpret_cast<const float4*>(ap + s * 32 + 4);
        }

        f32x4 acc[16] = {};
        #pragma unroll
        for (int s = 0; s < 8; ++s) {
            bf16x8 a = cvt8(buf[2 * s], buf[2 * s + 1]);
            int koff = (s * 64 + kg * 16) ^ xo;
            #pragma unroll
            for (int nt = 0; nt < 16; ++nt) {
                int n = nt * 16 + arow;
                bf16x8 b = *reinterpret_cast<const bf16x8*>(wlds + n * 512 + koff);
                acc[nt] = __builtin_amdgcn_mfma_f32_16x16x32_bf16(a, b, acc[nt], 0, 0, 0);
            }
        }

        // epilogue: lane stores rows R + kg*4 + rr; 4 col-groups g
        #pragma unroll
        for (int rr = 0; rr < 4; ++rr) {
            int row = R + kg * 4 + rr;
            #pragma unroll
            for (int g = 0; g < 4; ++g) {
                ushort4 h;
                h.x = f2bf(acc[4 * g + 0][rr]);
                h.y = f2bf(acc[4 * g + 1][rr]);
                h.z = f2bf(acc[4 * g + 2][rr]);
                h.w = f2bf(acc[4 * g + 3][rr]);
                *reinterpret_cast<ushort4*>(xp + (size_t)row * 256 + g * 64 + arow * 4) = h;
            }
        }
    }
}

// wave per out row; batched independent bf16-row gathers; fp32 out (unpermute).
__global__ __launch_bounds__(256) void gather_kernel(
    const unsigned short* __restrict__ xp, const float* __restrict__ csr_val,
    const int* __restrict__ csr_col, const int* __restrict__ off,
    float* __restrict__ out, int M)
{
    int row = blockIdx.x * 4 + (threadIdx.x >> 6);
    if (row >= M) return;
    int lane = threadIdx.x & 63;

    int s = off[row], e = off[row + 1];
    float a0 = 0.f, a1 = 0.f, a2 = 0.f, a3 = 0.f;

    for (int j = s; j < e; j += 8) {
        int nb = e - j;                         // wave-uniform
        int c[8]; float v[8]; ushort4 xs[8];
        #pragma unroll
        for (int t = 0; t < 8; ++t)
            if (t < nb) { c[t] = csr_col[j + t]; v[t] = csr_val[j + t]; }
        #pragma unroll
        for (int t = 0; t < 8; ++t)
            if (t < nb)
                xs[t] = *reinterpret_cast<const ushort4*>(
                    xp + (size_t)c[t] * 256 + lane * 4);   // 8B/lane, independent
        #pragma unroll
        for (int t = 0; t < 8; ++t)
            if (t < nb) {
                a0 += v[t] * bf2f(xs[t].x);
                a1 += v[t] * bf2f(xs[t].y);
                a2 += v[t] * bf2f(xs[t].z);
                a3 += v[t] * bf2f(xs[t].w);
            }
    }

    // lane holds true channels {64*(lane>>4) + (lane&15) + 16*t}
    int col0 = (lane >> 4) * 64 + (lane & 15);
    float* o = out + (size_t)row * 256;
    o[col0 +  0] = a0;
    o[col0 + 16] = a1;
    o[col0 + 32] = a2;
    o[col0 + 48] = a3;
}

extern "C" void kernel_launch(void* const* d_in, const int* in_sizes, int n_in,
                              void* d_out, int out_size, void* d_ws, size_t ws_size,
                              hipStream_t stream) {
    const float* x_src  = (const float*)d_in[0];
    const float* W      = (const float*)d_in[1];
    const float* b_vals = (const float*)d_in[2];
    const int*   b_rows = (const int*)d_in[3];
    const int*   b_cols = (const int*)d_in[4];

    const int C = 256;
    const int M = out_size / C;
    const int nnz = in_sizes[2];
    const int N = in_sizes[0] / C;

    char* ws = (char*)d_ws;
    unsigned short* Wt = (unsigned short*)ws;           ws += 256 * 256 * 2;
    int*   cnt     = (int*)ws;                          ws += (size_t)M * 4;
    int*   off     = (int*)ws;                          ws += (size_t)(M + 1) * 4;
    int*   cursor  = (int*)ws;                          ws += (size_t)M * 4;
    int*   partials= (int*)ws;                          ws += 64 * 4;
    int*   csr_col = (int*)ws;                          ws += (size_t)nnz * 4;
    float* csr_val = (float*)ws;                        ws += (size_t)nnz * 4;
    ws = (char*)(((size_t)ws + 63) & ~(size_t)63);
    unsigned short* xp = (unsigned short*)ws;           // N*512 bytes (~102 MB)

    float* out = (float*)d_out;

    hipMemsetAsync(cnt, 0, (size_t)M * 4, stream);

    wtrans_kernel<<<256, 256, 0, stream>>>(W, Wt);

    int nblk_nnz = (nnz + 255) / 256;
    hist_kernel<<<nblk_nnz, 256, 0, stream>>>(b_rows, cnt, nnz);

    int nb = (M + 4095) / 4096;
    scan_part_kernel<<<nb, 1024, 0, stream>>>(cnt, partials, M);
    scan_mid_kernel<<<1, 64, 0, stream>>>(partials, off, nb, M);
    scan_apply_kernel<<<nb, 1024, 0, stream>>>(cnt, partials, off, cursor, M);

    fill_kernel<<<nblk_nnz, 256, 0, stream>>>(b_vals, b_rows, b_cols, cursor,
                                              csr_col, csr_val, nnz);

    int ntiles = N / 16;                       // N=200000 -> 12500
    int grid_p = 256;
    int tpw = (ntiles + grid_p * 8 - 1) / (grid_p * 8);
    proj2_kernel<<<grid_p, 512, 0, stream>>>(x_src, Wt, xp, ntiles, tpw);

    gather_kernel<<<(M + 3) / 4, 256, 0, stream>>>(xp, csr_val, csr_col, off, out, M);
}

// Round 10
// 196.693 us; speedup vs baseline: 1.5900x; 1.0601x over previous
//
#include <hip/hip_runtime.h>

// out = B @ (X @ W):
//   wtrans: Wt_bf16[n][k] = bf16(W[k][n])
//   hist/scan/fill: CSR build
//   proj2:  x_proj_bf16 = bf16(X @ W). W entirely in LDS (128 KB, swizzled,
//           staged once per block). Block = 1024 thr (16 waves -> 4 waves/SIMD
//           at 1 block/CU); each wave streams 16-row A-tiles from fp32 X
//           (two 8-load bursts, <=128 VGPR), 128 MFMA/tile vs LDS B;
//           lane-permuted packed epilogue stores (contract shared with gather)
//   gather: wave per out row, batched independent 512B bf16-row gathers,
//           fp32 accumulate, direct fp32 out writes (unpermuting)

typedef short bf16x8 __attribute__((ext_vector_type(8)));
typedef float f32x4  __attribute__((ext_vector_type(4)));

static __device__ __forceinline__ unsigned short f2bf(float f) {
    union { float f; unsigned u; } a; a.f = f;
    unsigned r = a.u + 0x7FFFu + ((a.u >> 16) & 1u);   // RNE
    return (unsigned short)(r >> 16);
}

static __device__ __forceinline__ float bf2f(unsigned short h) {
    union { unsigned u; float f; } a; a.u = (unsigned)h << 16;
    return a.f;
}

static __device__ __forceinline__ unsigned pack2(float f0, float f1) {
    return (unsigned)f2bf(f0) | ((unsigned)f2bf(f1) << 16);
}

static __device__ __forceinline__ bf16x8 cvt8(float4 lo, float4 hi) {
    union { bf16x8 v; unsigned u[4]; } r;
    r.u[0] = pack2(lo.x, lo.y);
    r.u[1] = pack2(lo.z, lo.w);
    r.u[2] = pack2(hi.x, hi.y);
    r.u[3] = pack2(hi.z, hi.w);
    return r.v;
}

__global__ __launch_bounds__(256) void wtrans_kernel(
    const float* __restrict__ W, unsigned short* __restrict__ Wt)
{
    int k = blockIdx.x;
    int n = threadIdx.x;
    Wt[(size_t)n * 256 + k] = f2bf(W[(size_t)k * 256 + n]);
}

__global__ __launch_bounds__(256) void hist_kernel(
    const int* __restrict__ b_rows, int* __restrict__ cnt, int nnz)
{
    int i = blockIdx.x * 256 + threadIdx.x;
    if (i < nnz) atomicAdd(&cnt[b_rows[i]], 1);
}

__global__ __launch_bounds__(1024) void scan_part_kernel(
    const int* __restrict__ cnt, int* __restrict__ partials, int M)
{
    int tid = threadIdx.x;
    int base = blockIdx.x * 4096;
    int s = 0;
    #pragma unroll
    for (int k = 0; k < 4; ++k) {
        int i = base + k * 1024 + tid;
        if (i < M) s += cnt[i];
    }
    #pragma unroll
    for (int d = 1; d < 64; d <<= 1) s += __shfl_xor(s, d);
    __shared__ int wsum[16];
    int lane = tid & 63, wid = tid >> 6;
    if (lane == 0) wsum[wid] = s;
    __syncthreads();
    if (tid == 0) {
        int t = 0;
        #pragma unroll
        for (int w = 0; w < 16; ++w) t += wsum[w];
        partials[blockIdx.x] = t;
    }
}

__global__ __launch_bounds__(64) void scan_mid_kernel(
    int* __restrict__ partials, int* __restrict__ off, int np, int M)
{
    int lane = threadIdx.x;
    int v = (lane < np) ? partials[lane] : 0;
    int x = v;
    #pragma unroll
    for (int d = 1; d < 64; d <<= 1) { int y = __shfl_up(x, d); if (lane >= d) x += y; }
    if (lane < np) partials[lane] = x - v;
    if (lane == 63) off[M] = x;
}

__global__ __launch_bounds__(1024) void scan_apply_kernel(
    const int* __restrict__ cnt, const int* __restrict__ partials,
    int* __restrict__ off, int* __restrict__ cursor, int M)
{
    int tid = threadIdx.x;
    int base = blockIdx.x * 4096 + tid * 4;
    int4 v = make_int4(0, 0, 0, 0);
    if (base + 3 < M) v = *reinterpret_cast<const int4*>(cnt + base);
    else {
        if (base + 0 < M) v.x = cnt[base + 0];
        if (base + 1 < M) v.y = cnt[base + 1];
        if (base + 2 < M) v.z = cnt[base + 2];
    }
    int s1 = v.x + v.y, s2 = s1 + v.z, tsum = s2 + v.w;
    int x = tsum;
    int lane = tid & 63, wid = tid >> 6;
    #pragma unroll
    for (int d = 1; d < 64; d <<= 1) { int y = __shfl_up(x, d); if (lane >= d) x += y; }
    __shared__ int wsum[16];
    if (lane == 63) wsum[wid] = x;
    __syncthreads();
    if (wid == 0 && lane < 16) {
        int w = wsum[lane];
        int xx = w;
        #pragma unroll
        for (int d = 1; d < 16; d <<= 1) { int y = __shfl_up(xx, d); if (lane >= d) xx += y; }
        wsum[lane] = xx - w;
    }
    __syncthreads();
    int excl = (x - tsum) + wsum[wid] + partials[blockIdx.x];
    int o0 = excl, o1 = excl + v.x, o2 = excl + s1, o3 = excl + s2;
    if (base + 0 < M) { off[base + 0] = o0; cursor[base + 0] = o0; }
    if (base + 1 < M) { off[base + 1] = o1; cursor[base + 1] = o1; }
    if (base + 2 < M) { off[base + 2] = o2; cursor[base + 2] = o2; }
    if (base + 3 < M) { off[base + 3] = o3; cursor[base + 3] = o3; }
}

__global__ __launch_bounds__(256) void fill_kernel(
    const float* __restrict__ b_vals, const int* __restrict__ b_rows,
    const int* __restrict__ b_cols, int* __restrict__ cursor,
    int* __restrict__ csr_col, float* __restrict__ csr_val, int nnz)
{
    int i = blockIdx.x * 256 + threadIdx.x;
    if (i < nnz) {
        int r = b_rows[i];
        int pos = atomicAdd(&cursor[r], 1);
        csr_col[pos] = b_cols[i];
        csr_val[pos] = b_vals[i];
    }
}

// x_proj = bf16(X @ W) with W entirely in LDS; 16 waves/block (4/SIMD).
// LDS byte(n, koff) = n*512 + (koff ^ ((n&7)<<4)), koff = k*2.
// Wave processes 16-row tiles: tile = blk*(tpw*16) + it*16 + wid.
// Requires N % 16 == 0.
// xp storage permutation (contract with gather_kernel): row halfword
// [g*64 + a*4 + t] holds true channel {64g + a + 16t}, a=0..15, t=0..3.
__global__ __launch_bounds__(1024, 4) void proj2_kernel(
    const float* __restrict__ X, const unsigned short* __restrict__ Wt,
    unsigned short* __restrict__ xp, int ntiles, int tpw)
{
    __shared__ __align__(16) unsigned char wlds[256 * 512];   // 128 KB

    int tid = threadIdx.x;
    int lane = tid & 63, wid = tid >> 6;

    // ---- stage Wt -> LDS (reg-staged 16B chunks, swizzled store)
    const char* wtg = reinterpret_cast<const char*>(Wt);
    #pragma unroll
    for (int itc = 0; itc < 8; ++itc) {
        int c = tid + itc * 1024;              // chunk 0..8191
        int n = c >> 5, j = c & 31;
        uint4 w16 = *reinterpret_cast<const uint4*>(wtg + (size_t)n * 512 + j * 16);
        int b = n * 512 + ((j * 16) ^ ((n & 7) << 4));
        *reinterpret_cast<uint4*>(wlds + b) = w16;
    }
    __syncthreads();

    int arow = lane & 15;
    int kg = lane >> 4;                        // 0..3
    int xo = (arow & 7) << 4;                  // read-side swizzle (n&7 == arow&7)

    for (int it = 0; it < tpw; ++it) {
        int tile = blockIdx.x * (tpw << 4) + (it << 4) + wid;
        if (tile >= ntiles) break;
        int R = tile * 16;

        const float* ap = X + (size_t)(R + arow) * 256 + kg * 8;

        f32x4 acc[16] = {};
        #pragma unroll
        for (int half = 0; half < 2; ++half) {
            float4 buf[8];
            #pragma unroll
            for (int s = 0; s < 4; ++s) {      // 8 independent 16B loads
                int ss = half * 4 + s;
                buf[2 * s]     = *reinterpret_cast<const float4*>(ap + ss * 32);
                buf[2 * s + 1] = *reinterpret_cast<const float4*>(ap + ss * 32 + 4);
            }
            #pragma unroll
            for (int s = 0; s < 4; ++s) {
                int ss = half * 4 + s;
                bf16x8 a = cvt8(buf[2 * s], buf[2 * s + 1]);
                int koff = (ss * 64 + kg * 16) ^ xo;
                #pragma unroll
                for (int nt = 0; nt < 16; ++nt) {
                    int n = nt * 16 + arow;
                    bf16x8 b = *reinterpret_cast<const bf16x8*>(wlds + n * 512 + koff);
                    acc[nt] = __builtin_amdgcn_mfma_f32_16x16x32_bf16(a, b, acc[nt], 0, 0, 0);
                }
            }
        }

        // epilogue: lane stores rows R + kg*4 + rr; 4 col-groups g
        #pragma unroll
        for (int rr = 0; rr < 4; ++rr) {
            int row = R + kg * 4 + rr;
            #pragma unroll
            for (int g = 0; g < 4; ++g) {
                ushort4 h;
                h.x = f2bf(acc[4 * g + 0][rr]);
                h.y = f2bf(acc[4 * g + 1][rr]);
                h.z = f2bf(acc[4 * g + 2][rr]);
                h.w = f2bf(acc[4 * g + 3][rr]);
                *reinterpret_cast<ushort4*>(xp + (size_t)row * 256 + g * 64 + arow * 4) = h;
            }
        }
    }
}

// wave per out row; batched independent bf16-row gathers; fp32 out (unpermute).
__global__ __launch_bounds__(256) void gather_kernel(
    const unsigned short* __restrict__ xp, const float* __restrict__ csr_val,
    const int* __restrict__ csr_col, const int* __restrict__ off,
    float* __restrict__ out, int M)
{
    int row = blockIdx.x * 4 + (threadIdx.x >> 6);
    if (row >= M) return;
    int lane = threadIdx.x & 63;

    int s = off[row], e = off[row + 1];
    float a0 = 0.f, a1 = 0.f, a2 = 0.f, a3 = 0.f;

    for (int j = s; j < e; j += 8) {
        int nb = e - j;                         // wave-uniform
        int c[8]; float v[8]; ushort4 xs[8];
        #pragma unroll
        for (int t = 0; t < 8; ++t)
            if (t < nb) { c[t] = csr_col[j + t]; v[t] = csr_val[j + t]; }
        #pragma unroll
        for (int t = 0; t < 8; ++t)
            if (t < nb)
                xs[t] = *reinterpret_cast<const ushort4*>(
                    xp + (size_t)c[t] * 256 + lane * 4);   // 8B/lane, independent
        #pragma unroll
        for (int t = 0; t < 8; ++t)
            if (t < nb) {
                a0 += v[t] * bf2f(xs[t].x);
                a1 += v[t] * bf2f(xs[t].y);
                a2 += v[t] * bf2f(xs[t].z);
                a3 += v[t] * bf2f(xs[t].w);
            }
    }

    // lane holds true channels {64*(lane>>4) + (lane&15) + 16*t}
    int col0 = (lane >> 4) * 64 + (lane & 15);
    float* o = out + (size_t)row * 256;
    o[col0 +  0] = a0;
    o[col0 + 16] = a1;
    o[col0 + 32] = a2;
    o[col0 + 48] = a3;
}

extern "C" void kernel_launch(void* const* d_in, const int* in_sizes, int n_in,
                              void* d_out, int out_size, void* d_ws, size_t ws_size,
                              hipStream_t stream) {
    const float* x_src  = (const float*)d_in[0];
    const float* W      = (const float*)d_in[1];
    const float* b_vals = (const float*)d_in[2];
    const int*   b_rows = (const int*)d_in[3];
    const int*   b_cols = (const int*)d_in[4];

    const int C = 256;
    const int M = out_size / C;
    const int nnz = in_sizes[2];
    const int N = in_sizes[0] / C;

    char* ws = (char*)d_ws;
    unsigned short* Wt = (unsigned short*)ws;           ws += 256 * 256 * 2;
    int*   cnt     = (int*)ws;                          ws += (size_t)M * 4;
    int*   off     = (int*)ws;                          ws += (size_t)(M + 1) * 4;
    int*   cursor  = (int*)ws;                          ws += (size_t)M * 4;
    int*   partials= (int*)ws;                          ws += 64 * 4;
    int*   csr_col = (int*)ws;                          ws += (size_t)nnz * 4;
    float* csr_val = (float*)ws;                        ws += (size_t)nnz * 4;
    ws = (char*)(((size_t)ws + 63) & ~(size_t)63);
    unsigned short* xp = (unsigned short*)ws;           // N*512 bytes (~102 MB)

    float* out = (float*)d_out;

    hipMemsetAsync(cnt, 0, (size_t)M * 4, stream);

    wtrans_kernel<<<256, 256, 0, stream>>>(W, Wt);

    int nblk_nnz = (nnz + 255) / 256;
    hist_kernel<<<nblk_nnz, 256, 0, stream>>>(b_rows, cnt, nnz);

    int nb = (M + 4095) / 4096;
    scan_part_kernel<<<nb, 1024, 0, stream>>>(cnt, partials, M);
    scan_mid_kernel<<<1, 64, 0, stream>>>(partials, off, nb, M);
    scan_apply_kernel<<<nb, 1024, 0, stream>>>(cnt, partials, off, cursor, M);

    fill_kernel<<<nblk_nnz, 256, 0, stream>>>(b_vals, b_rows, b_cols, cursor,
                                              csr_col, csr_val, nnz);

    int ntiles = N / 16;                       // N=200000 -> 12500
    int grid_p = 256;
    int tpw = (ntiles + grid_p * 16 - 1) / (grid_p * 16);   // 4
    proj2_kernel<<<grid_p, 1024, 0, stream>>>(x_src, Wt, xp, ntiles, tpw);

    gather_kernel<<<(M + 3) / 4, 256, 0, stream>>>(xp, csr_val, csr_col, off, out, M);
}